// Round 7
// baseline (311.388 us; speedup 1.0000x reference)
//
#include <hip/hip_runtime.h>
#include <math.h>

#define ALPHA 0.2f
#define BETA 1.0f
#define EPSV 1e-8f
#define LOG2E 1.4426950408889634f
#define LN2 0.6931471805599453f

#define BATCH 4096
#define RR 18
#define KT 17            // R-1 targets per row
#define DD 256
#define NTGT (BATCH*KT)  // 69632 total targets

#define BMW 64           // anchors per wave
#define NWAVES 4
#define BMB (BMW*NWAVES) // 256 anchors per block
#define MBLK (BATCH/BMB) // 16
#define BN 64            // targets per LDS chunk
#define NCHUNKT (NTGT/BN)    // 1088 total chunks
#define NSPLIT 136           // N splits -> grid 2176, NCHUNK 8
#define NCHUNK (NCHUNKT/NSPLIT) // 8
#define NSLOT (NSPLIT*2)     // 272 per-anchor partial slots
#define CHUNK_BYTES (BN*DD)  // 16384 fp8, fragment-ordered

typedef int   i32x8  __attribute__((ext_vector_type(8)));
typedef float f32x16 __attribute__((ext_vector_type(16)));

__device__ inline void gl_lds16(const void* g, void* l){
  __builtin_amdgcn_global_load_lds(
      (const __attribute__((address_space(1))) unsigned int*)g,
      (__attribute__((address_space(3))) unsigned int*)l, 16, 0, 0);
}

__device__ inline int pk8(float a, float b, float c, float d){
  int p = __builtin_amdgcn_cvt_pk_fp8_f32(a, b, 0, false);
  return  __builtin_amdgcn_cvt_pk_fp8_f32(c, d, p, true);
}

__device__ inline i32x8 ld8_2(const unsigned char* plo, const unsigned char* phi){
  uint4 lo = *(const uint4*)plo, hi = *(const uint4*)phi;
  return (i32x8){(int)lo.x,(int)lo.y,(int)lo.z,(int)lo.w,
                 (int)hi.x,(int)hi.y,(int)hi.z,(int)hi.w};
}

// tbf8: chunk c (16 KB) holds targets t in [c*64,(c+1)*64). Region index
// u = 4*ki + 2*mt + w (1 KB each); slot = half*512 + m*16 (+q*4 for tconv).
// Gemm lane l (m=l&31, half=l>>5) reads region*1024 + l*16 -> lane-linear.
// afrag: anchor group g (32 anchors, 8 KB): region (g*4+ki)*2048 holds
// lane*32 + {0,16} for k in [ki*64 + half*32, +32).

// ---------------- Kernel 1: chunk-major fp8 convert + cos + diag -------------
// Block c: 64 target rows (r=tid>>2, q=tid&3), fully-coalesced stores.
// Blocks 0..255 additionally convert 16 anchors each into afrag order.
__global__ __launch_bounds__(256) void tconv_kernel(
    const float* __restrict__ feat, const float* __restrict__ lscale,
    unsigned char* __restrict__ abf8, unsigned char* __restrict__ tbf8,
    float* __restrict__ carr, float* __restrict__ diag){
  int c = blockIdx.x, tid = threadIdx.x;
  int r = tid >> 2, q = tid & 3;
  int t = c*64 + r;
  unsigned tb = (unsigned)t / 17u;
  unsigned tk = (unsigned)t - tb*17u;
  const float* trow = feat + ((size_t)tb*RR + tk + 1)*DD;
  const float* arow = feat + (size_t)tb*RR*DD;
  float d = 0.f, qq = 0.f, asq = 0.f;
  unsigned pkv[16];
  #pragma unroll
  for (int i=0;i<16;++i){              // k = 16*i + 4*q + {0..3}
    float4 tv = ((const float4*)trow)[q + 4*i];
    float4 av = ((const float4*)arow)[q + 4*i];
    d   += av.x*tv.x + av.y*tv.y + av.z*tv.z + av.w*tv.w;
    qq  += tv.x*tv.x + tv.y*tv.y + tv.z*tv.z + tv.w*tv.w;
    asq += av.x*av.x + av.y*av.y + av.z*av.z + av.w*av.w;
    pkv[i] = (unsigned)pk8(tv.x, tv.y, tv.z, tv.w);
  }
  int m = r & 31, mt = r >> 5;
  size_t cb = (size_t)c*CHUNK_BYTES;
  #pragma unroll
  for (int i=0;i<16;++i){              // slot u=i: every store instr = 256 B run
    int ki = i >> 2, hf = (i >> 1) & 1, w = i & 1;
    *(unsigned*)(tbf8 + cb + (size_t)((ki*2+mt)*2+w)*1024 + hf*512 + m*16 + q*4)
        = pkv[i];
  }
  d   += __shfl_xor(d,1);   d   += __shfl_xor(d,2);
  qq  += __shfl_xor(qq,1);  qq  += __shfl_xor(qq,2);
  asq += __shfl_xor(asq,1); asq += __shfl_xor(asq,2);
  if (q == 0){
    float an = fmaxf(sqrtf(asq), EPSV), tn = fmaxf(sqrtf(qq), EPSV);
    carr[t] = d / (an*tn);
    if (tk == 0) diag[tb] = d;         // raw fp32 anchor.pos
  }
  if (c < 256){                        // anchors b in [c*16, c*16+16)
    int a = tid >> 4, j = tid & 15;    // j = 16-float piece of the row
    int b = c*16 + a;
    const float* ar = feat + (size_t)b*RR*DD + j*16;
    float s2 = lscale[0]*LOG2E;
    unsigned o0, o1, o2, o3;
    { float4 v=((const float4*)ar)[0]; o0=(unsigned)pk8(v.x*s2,v.y*s2,v.z*s2,v.w*s2); }
    { float4 v=((const float4*)ar)[1]; o1=(unsigned)pk8(v.x*s2,v.y*s2,v.z*s2,v.w*s2); }
    { float4 v=((const float4*)ar)[2]; o2=(unsigned)pk8(v.x*s2,v.y*s2,v.z*s2,v.w*s2); }
    { float4 v=((const float4*)ar)[3]; o3=(unsigned)pk8(v.x*s2,v.y*s2,v.z*s2,v.w*s2); }
    int g = b >> 5, l31a = b & 31, ki = j >> 2, hf = (j >> 1) & 1, six = j & 1;
    *(uint4*)(abf8 + (size_t)(g*4+ki)*2048 + (size_t)(hf*32 + l31a)*32 + six*16)
        = make_uint4(o0,o1,o2,o3);
  }
}

// ---------------- Kernel 2: MX-fp8 32x32x64 MFMA + online log2-sum-exp2 ------
// Anchors reloaded per chunk from afrag (coalesced b128, L2-hot) instead of
// pinned in 64 VGPRs -> 4 waves/SIMD. Double-buffered LDS, 1 barrier/chunk.
__global__ __launch_bounds__(256,4) void gemm_lse_kernel(
    const unsigned char* __restrict__ afrag, const unsigned char* __restrict__ tbf8,
    float* __restrict__ part_m, float* __restrict__ part_s){
  __shared__ __align__(16) unsigned char Bs[2][CHUNK_BYTES];   // 2 x 16 KB
  const int tid = threadIdx.x, lane = tid & 63, wave = tid >> 6;
  const int mb = blockIdx.y, ns = blockIdx.x;
  const int l31 = lane & 31, half = lane >> 5;

  const char* gbase = (const char*)tbf8 + (size_t)(ns*NCHUNK)*CHUNK_BYTES;
  auto stage = [&](int ch){
    const char* g = gbase + (size_t)ch*CHUNK_BYTES;
    char* l = (char*)Bs[ch & 1];
    #pragma unroll
    for (int j=0;j<4;++j){
      int off = j*4096 + tid*16;
      gl_lds16(g + off, l + off);
    }
  };
  stage(0);

  const unsigned char* ap0 = afrag + (size_t)(mb*8 + wave*2)*8192 + lane*32;
  const unsigned char* ap1 = ap0 + 8192;

  float run_m[2] = {-INFINITY,-INFINITY};
  float run_s[2] = {0.f,0.f};

  for (int ch=0; ch<NCHUNK; ++ch){
    __syncthreads();                   // DMA for ch drained; buf[ch^1] free
    if (ch+1 < NCHUNK) stage(ch+1);
    const unsigned char* frag = &Bs[ch&1][0] + lane*16;

    f32x16 a00=(f32x16)(0.f), a01=(f32x16)(0.f);
    f32x16 a10=(f32x16)(0.f), a11=(f32x16)(0.f);

    #pragma unroll
    for (int ki=0; ki<4; ++ki){
      i32x8 af0 = ld8_2(ap0 + ki*2048, ap0 + ki*2048 + 16);
      i32x8 af1 = ld8_2(ap1 + ki*2048, ap1 + ki*2048 + 16);
      i32x8 tf0 = ld8_2(frag + (size_t)(ki*4+0)*1024, frag + (size_t)(ki*4+1)*1024);
      i32x8 tf1 = ld8_2(frag + (size_t)(ki*4+2)*1024, frag + (size_t)(ki*4+3)*1024);
      a00 = __builtin_amdgcn_mfma_scale_f32_32x32x64_f8f6f4(tf0, af0, a00, 0,0, 0,127, 0,127);
      a01 = __builtin_amdgcn_mfma_scale_f32_32x32x64_f8f6f4(tf0, af1, a01, 0,0, 0,127, 0,127);
      a10 = __builtin_amdgcn_mfma_scale_f32_32x32x64_f8f6f4(tf1, af0, a10, 0,0, 0,127, 0,127);
      a11 = __builtin_amdgcn_mfma_scale_f32_32x32x64_f8f6f4(tf1, af1, a11, 0,0, 0,127, 0,127);
    }

    // epilogue (log2 domain), per nt over both m-tiles (u,v)
    #pragma unroll
    for (int nt=0; nt<2; ++nt){
      const f32x16& u = nt ? a01 : a00;
      const f32x16& v = nt ? a11 : a10;
      f32x16 tm = __builtin_elementwise_max(u, v);
      float m8[8];
      #pragma unroll
      for (int i=0;i<8;++i) m8[i] = fmaxf(tm[i], tm[i+8]);
      float mx = fmaxf(fmaxf(fmaxf(m8[0],m8[1]),fmaxf(m8[2],m8[3])),
                       fmaxf(fmaxf(m8[4],m8[5]),fmaxf(m8[6],m8[7])));
      f32x16 e;
      #pragma unroll
      for (int i=0;i<16;++i)
        e[i] = __builtin_amdgcn_exp2f(u[i]-mx) + __builtin_amdgcn_exp2f(v[i]-mx);
      float s8[8];
      #pragma unroll
      for (int i=0;i<8;++i) s8[i] = e[i] + e[i+8];
      float sh = ((s8[0]+s8[1])+(s8[2]+s8[3]))+((s8[4]+s8[5])+(s8[6]+s8[7]));
      float nm = fmaxf(run_m[nt], mx);
      run_s[nt] = run_s[nt]*__builtin_amdgcn_exp2f(run_m[nt]-nm)
                + sh*__builtin_amdgcn_exp2f(mx-nm);
      run_m[nt] = nm;
    }
  }

  #pragma unroll
  for (int nt=0; nt<2; ++nt){
    int gm = mb*BMB + wave*BMW + nt*32 + l31;
    int slot = ns*2 + half;
    part_m[(size_t)gm*NSLOT + slot] = run_m[nt];
    part_s[(size_t)gm*NSLOT + slot] = run_s[nt];
  }
}

// ---------------- Kernel 3: combine partials + KL (one wave per b) -----------
__global__ __launch_bounds__(256) void combine_kernel(
    const float* __restrict__ part_m, const float* __restrict__ part_s,
    const float* __restrict__ diag, const float* __restrict__ carr,
    const float* __restrict__ scores, const float* __restrict__ lscale,
    float* __restrict__ outarr){
  int lane = threadIdx.x & 63, wv = threadIdx.x >> 6;
  int b = blockIdx.x*4 + wv;
  float s = lscale[0];
  const float* pm = part_m + (size_t)b*NSLOT;
  const float* ps = part_s + (size_t)b*NSLOT;
  float mv[5], sv[5];
  float M = -INFINITY;
  #pragma unroll
  for (int i=0;i<5;++i){
    int idx = lane + i*64;
    bool ok = (idx < NSLOT);
    mv[i] = ok ? pm[idx] : -INFINITY;
    sv[i] = ok ? ps[idx] : 0.f;
    M = fmaxf(M, mv[i]);
  }
  #pragma unroll
  for (int off=1; off<64; off<<=1) M = fmaxf(M, __shfl_xor(M,off));
  float S = 0.f;
  #pragma unroll
  for (int i=0;i<5;++i) S += sv[i]*__builtin_amdgcn_exp2f(mv[i]-M);
  #pragma unroll
  for (int off=1; off<64; off<<=1) S += __shfl_xor(S,off);
  float inf = (M + __log2f(S))*LN2 - s*diag[b];   // back to ln domain

  // KL (uniform across lanes; loads broadcast from L1)
  const float* cb = carr + (size_t)b*KT;
  const float* sb = scores + (size_t)b*KT;
  float cv[KT], sw[KT];
  #pragma unroll
  for (int j=0;j<KT;++j){ cv[j] = cb[j]; sw[j] = sb[j]; }
  float cm = -INFINITY, sm = -INFINITY;
  #pragma unroll
  for (int j=0;j<KT;++j){ cm = fmaxf(cm, cv[j]); sm = fmaxf(sm, sw[j]); }
  float cs = 0.f, ss = 0.f;
  #pragma unroll
  for (int j=0;j<KT;++j){
    cs += __builtin_amdgcn_exp2f((cv[j]-cm)*LOG2E);
    ss += __builtin_amdgcn_exp2f((sw[j]-sm)*LOG2E);
  }
  float lse_c = cm + __logf(cs);
  float lse_s = sm + __logf(ss);
  float kl = 0.f;
  #pragma unroll
  for (int j=0;j<KT;++j){
    float lq = sw[j] - lse_s;
    float lp = cv[j] - lse_c;
    kl += __builtin_amdgcn_exp2f(lq*LOG2E)*(lq - lp);
  }
  kl *= (1.0f/KT);
  if (lane == 0) outarr[b] = BETA*kl + ALPHA*inf;
}

// ---------------- Kernel 4: final mean ---------------------------------------
__global__ __launch_bounds__(256) void final_kernel(
    const float* __restrict__ outarr, float* __restrict__ out){
  __shared__ float sh[4];
  int tid = threadIdx.x, lane = tid & 63, wv = tid >> 6;
  float v = 0.f;
  for (int i = tid; i < BATCH; i += 256) v += outarr[i];
  #pragma unroll
  for (int off=1; off<64; off<<=1) v += __shfl_xor(v, off);
  if (lane == 0) sh[wv] = v;
  __syncthreads();
  if (tid == 0) out[0] = (sh[0]+sh[1]+sh[2]+sh[3])*(1.0f/BATCH);
}

extern "C" void kernel_launch(void* const* d_in, const int* in_sizes, int n_in,
                              void* d_out, int out_size, void* d_ws, size_t ws_size,
                              hipStream_t stream){
  const float* feat   = (const float*)d_in[0];
  const float* scores = (const float*)d_in[1];
  // d_in[2] row_sizes: shape-only, unused
  const float* lscale = (const float*)d_in[3];

  float* ws     = (float*)d_ws;
  float* diag   = ws;                                   // 4096
  float* outarr = diag + BATCH;                         // 4096
  float* carr   = outarr + BATCH;                       // 69632
  float* part_m = carr + NTGT;                          // 4096*272
  float* part_s = part_m + (size_t)BATCH*NSLOT;         // 4096*272
  unsigned char* abf8 = (unsigned char*)(part_s + (size_t)BATCH*NSLOT); // 1 MB
  unsigned char* tbf8 = abf8 + (size_t)128*8192;        // 69632*256 fp8

  tconv_kernel<<<NCHUNKT, 256, 0, stream>>>(feat, lscale, abf8, tbf8, carr, diag);
  gemm_lse_kernel<<<dim3(NSPLIT, MBLK), 256, 0, stream>>>(abf8, tbf8, part_m, part_s);
  combine_kernel<<<BATCH/4, 256, 0, stream>>>(part_m, part_s, diag, carr, scores,
                                              lscale, outarr);
  final_kernel<<<1, 256, 0, stream>>>(outarr, (float*)d_out);
}

// Round 8
// 199.826 us; speedup vs baseline: 1.5583x; 1.5583x over previous
//
#include <hip/hip_runtime.h>
#include <math.h>

#define ALPHA 0.2f
#define BETA 1.0f
#define EPSV 1e-8f
#define LOG2E 1.4426950408889634f
#define LN2 0.6931471805599453f

#define BATCH 4096
#define RR 18
#define KT 17            // R-1 targets per row
#define DD 256
#define NTGT (BATCH*KT)  // 69632 total targets

#define BMW 32           // anchors per wave (1 x 32-tile, frags in 32 VGPRs)
#define NWAVES 4
#define BMB (BMW*NWAVES) // 128 anchors per block
#define MBLK (BATCH/BMB) // 32
#define BN 64            // targets per LDS chunk
#define NCHUNKT (NTGT/BN)    // 1088 total chunks
#define NSPLIT 64            // N splits -> grid 2048
#define NCHUNK (NCHUNKT/NSPLIT) // 17
#define NSLOT (NSPLIT*2)     // 128 per-anchor partial slots
#define CHUNK_BYTES (BN*DD)  // 16384 fp8, fragment-ordered

typedef int   i32x8  __attribute__((ext_vector_type(8)));
typedef float f32x16 __attribute__((ext_vector_type(16)));

__device__ inline void gl_lds16(const void* g, void* l){
  __builtin_amdgcn_global_load_lds(
      (const __attribute__((address_space(1))) unsigned int*)g,
      (__attribute__((address_space(3))) unsigned int*)l, 16, 0, 0);
}

__device__ inline int pk8(float a, float b, float c, float d){
  int p = __builtin_amdgcn_cvt_pk_fp8_f32(a, b, 0, false);
  return  __builtin_amdgcn_cvt_pk_fp8_f32(c, d, p, true);
}

__device__ inline i32x8 ld8_2(const unsigned char* plo, const unsigned char* phi){
  uint4 lo = *(const uint4*)plo, hi = *(const uint4*)phi;
  return (i32x8){(int)lo.x,(int)lo.y,(int)lo.z,(int)lo.w,
                 (int)hi.x,(int)hi.y,(int)hi.z,(int)hi.w};
}

// tbf8: chunk c (16 KB) holds targets t in [c*64,(c+1)*64). Region index
// u = (ki*2+mt)*2+w (1 KB each); inner offset hf*512 + m*16 + q*4.
// Gemm lane l (m=l&31, half=l>>5) reads region*1024 + lane*16 -> lane-linear.
// abf8: row-major [b][k] fp8, pre-scaled by s*log2e (B-operand loads strided,
// once per kernel).

// ---------------- Kernel 1: chunk-major fp8 convert + cos + diag -------------
// Block c: 64 target rows (r=tid>>2, q=tid&3); every store instr = 256-B run.
// Blocks 0..255 additionally convert 16 anchors each (row-major out).
__global__ __launch_bounds__(256) void tconv_kernel(
    const float* __restrict__ feat, const float* __restrict__ lscale,
    unsigned char* __restrict__ abf8, unsigned char* __restrict__ tbf8,
    float* __restrict__ carr, float* __restrict__ diag){
  int c = blockIdx.x, tid = threadIdx.x;
  int r = tid >> 2, q = tid & 3;
  int t = c*64 + r;
  unsigned tb = (unsigned)t / 17u;
  unsigned tk = (unsigned)t - tb*17u;
  const float* trow = feat + ((size_t)tb*RR + tk + 1)*DD;
  const float* arow = feat + (size_t)tb*RR*DD;
  float d = 0.f, qq = 0.f, asq = 0.f;
  unsigned pkv[16];
  #pragma unroll
  for (int i=0;i<16;++i){              // k = 16*i + 4*q + {0..3}
    float4 tv = ((const float4*)trow)[q + 4*i];
    float4 av = ((const float4*)arow)[q + 4*i];
    d   += av.x*tv.x + av.y*tv.y + av.z*tv.z + av.w*tv.w;
    qq  += tv.x*tv.x + tv.y*tv.y + tv.z*tv.z + tv.w*tv.w;
    asq += av.x*av.x + av.y*av.y + av.z*av.z + av.w*av.w;
    pkv[i] = (unsigned)pk8(tv.x, tv.y, tv.z, tv.w);
  }
  int m = r & 31, mt = r >> 5;
  size_t cb = (size_t)c*CHUNK_BYTES;
  #pragma unroll
  for (int i=0;i<16;++i){
    int ki = i >> 2, hf = (i >> 1) & 1, w = i & 1;
    *(unsigned*)(tbf8 + cb + (size_t)((ki*2+mt)*2+w)*1024 + hf*512 + m*16 + q*4)
        = pkv[i];
  }
  d   += __shfl_xor(d,1);   d   += __shfl_xor(d,2);
  qq  += __shfl_xor(qq,1);  qq  += __shfl_xor(qq,2);
  asq += __shfl_xor(asq,1); asq += __shfl_xor(asq,2);
  if (q == 0){
    float an = fmaxf(sqrtf(asq), EPSV), tn = fmaxf(sqrtf(qq), EPSV);
    carr[t] = d / (an*tn);
    if (tk == 0) diag[tb] = d;         // raw fp32 anchor.pos
  }
  if (c < 256){                        // anchors b in [c*16, c*16+16), row-major
    int a = tid >> 4, j = tid & 15;    // j = 16-float piece of the row
    int b = c*16 + a;
    const float* ar = feat + (size_t)b*RR*DD + j*16;
    float s2 = lscale[0]*LOG2E;
    unsigned o0, o1, o2, o3;
    { float4 v=((const float4*)ar)[0]; o0=(unsigned)pk8(v.x*s2,v.y*s2,v.z*s2,v.w*s2); }
    { float4 v=((const float4*)ar)[1]; o1=(unsigned)pk8(v.x*s2,v.y*s2,v.z*s2,v.w*s2); }
    { float4 v=((const float4*)ar)[2]; o2=(unsigned)pk8(v.x*s2,v.y*s2,v.z*s2,v.w*s2); }
    { float4 v=((const float4*)ar)[3]; o3=(unsigned)pk8(v.x*s2,v.y*s2,v.z*s2,v.w*s2); }
    *(uint4*)(abf8 + (size_t)b*DD + j*16) = make_uint4(o0,o1,o2,o3);
  }
}

// ---------------- Kernel 2: MX-fp8 32x32x64 MFMA + online log2-sum-exp2 ------
// D[m=target][n=anchor], scales=1.0 (e8m0 127). B-operand (32 anchors) pinned
// in 32 VGPRs; acc 32 AGPRs -> ~110 regs -> 4 waves/SIMD, 4 blocks/CU.
// Double-buffered LDS DMA, one barrier per chunk.
__global__ __launch_bounds__(256,4) void gemm_lse_kernel(
    const unsigned char* __restrict__ abf8, const unsigned char* __restrict__ tbf8,
    float* __restrict__ part_m, float* __restrict__ part_s){
  __shared__ __align__(16) unsigned char Bs[2][CHUNK_BYTES];   // 2 x 16 KB
  const int tid = threadIdx.x, lane = tid & 63, wave = tid >> 6;
  const int mb = blockIdx.y, ns = blockIdx.x;
  const int l31 = lane & 31, half = lane >> 5;

  const char* gbase = (const char*)tbf8 + (size_t)(ns*NCHUNK)*CHUNK_BYTES;
  auto stage = [&](int ch){
    const char* g = gbase + (size_t)ch*CHUNK_BYTES;
    char* l = (char*)Bs[ch & 1];
    #pragma unroll
    for (int j=0;j<4;++j){
      int off = j*4096 + tid*16;
      gl_lds16(g + off, l + off);
    }
  };
  stage(0);   // DMA in flight while we fetch anchor frags

  // anchor B-operand frags (once per kernel): n=l31, k=ki*64+half*32+[0,32)
  i32x8 af[4];
  {
    const unsigned char* ab = abf8
        + (size_t)(mb*BMB + wave*BMW + l31)*DD + half*32;
    #pragma unroll
    for (int ki=0;ki<4;++ki)
      af[ki] = ld8_2(ab + ki*64, ab + ki*64 + 16);
  }

  float run_m = -INFINITY, run_s = 0.f;

  for (int ch=0; ch<NCHUNK; ++ch){
    __syncthreads();                   // DMA for ch drained; buf[ch^1] free
    if (ch+1 < NCHUNK) stage(ch+1);
    const unsigned char* frag = &Bs[ch&1][0] + lane*16;

    f32x16 a0 = (f32x16)(0.f), a1 = (f32x16)(0.f);
    #pragma unroll
    for (int ki=0; ki<4; ++ki){
      i32x8 tf0 = ld8_2(frag + (size_t)(ki*4+0)*1024, frag + (size_t)(ki*4+1)*1024);
      i32x8 tf1 = ld8_2(frag + (size_t)(ki*4+2)*1024, frag + (size_t)(ki*4+3)*1024);
      a0 = __builtin_amdgcn_mfma_scale_f32_32x32x64_f8f6f4(tf0, af[ki], a0, 0,0, 0,127, 0,127);
      a1 = __builtin_amdgcn_mfma_scale_f32_32x32x64_f8f6f4(tf1, af[ki], a1, 0,0, 0,127, 0,127);
    }

    // epilogue (log2 domain): in-lane over 32 m-values for anchor col l31
    f32x16 tm = __builtin_elementwise_max(a0, a1);
    float m8[8];
    #pragma unroll
    for (int i=0;i<8;++i) m8[i] = fmaxf(tm[i], tm[i+8]);
    float mx = fmaxf(fmaxf(fmaxf(m8[0],m8[1]),fmaxf(m8[2],m8[3])),
                     fmaxf(fmaxf(m8[4],m8[5]),fmaxf(m8[6],m8[7])));
    f32x16 e;
    #pragma unroll
    for (int i=0;i<16;++i)
      e[i] = __builtin_amdgcn_exp2f(a0[i]-mx) + __builtin_amdgcn_exp2f(a1[i]-mx);
    float s8[8];
    #pragma unroll
    for (int i=0;i<8;++i) s8[i] = e[i] + e[i+8];
    float sh = ((s8[0]+s8[1])+(s8[2]+s8[3]))+((s8[4]+s8[5])+(s8[6]+s8[7]));
    float nm = fmaxf(run_m, mx);
    run_s = run_s*__builtin_amdgcn_exp2f(run_m-nm)
          + sh*__builtin_amdgcn_exp2f(mx-nm);
    run_m = nm;
  }

  int gm = mb*BMB + wave*BMW + l31;
  int slot = ns*2 + half;
  part_m[(size_t)gm*NSLOT + slot] = run_m;
  part_s[(size_t)gm*NSLOT + slot] = run_s;
}

// ---------------- Kernel 3: combine partials + KL (one wave per b) -----------
__global__ __launch_bounds__(256) void combine_kernel(
    const float* __restrict__ part_m, const float* __restrict__ part_s,
    const float* __restrict__ diag, const float* __restrict__ carr,
    const float* __restrict__ scores, const float* __restrict__ lscale,
    float* __restrict__ outarr){
  int lane = threadIdx.x & 63, wv = threadIdx.x >> 6;
  int b = blockIdx.x*4 + wv;
  float s = lscale[0];
  const float* pm = part_m + (size_t)b*NSLOT;
  const float* ps = part_s + (size_t)b*NSLOT;
  float m0 = pm[lane], m1 = pm[lane+64];
  float v0 = ps[lane], v1 = ps[lane+64];
  float M = fmaxf(m0, m1);
  #pragma unroll
  for (int off=1; off<64; off<<=1) M = fmaxf(M, __shfl_xor(M, off));
  float S = v0*__builtin_amdgcn_exp2f(m0-M) + v1*__builtin_amdgcn_exp2f(m1-M);
  #pragma unroll
  for (int off=1; off<64; off<<=1) S += __shfl_xor(S, off);
  float inf = (M + __log2f(S))*LN2 - s*diag[b];   // back to ln domain

  // KL (uniform across lanes; loads broadcast from L1)
  const float* cb = carr + (size_t)b*KT;
  const float* sb = scores + (size_t)b*KT;
  float cv[KT], sw[KT];
  #pragma unroll
  for (int j=0;j<KT;++j){ cv[j] = cb[j]; sw[j] = sb[j]; }
  float cm = -INFINITY, sm = -INFINITY;
  #pragma unroll
  for (int j=0;j<KT;++j){ cm = fmaxf(cm, cv[j]); sm = fmaxf(sm, sw[j]); }
  float cs = 0.f, ss = 0.f;
  #pragma unroll
  for (int j=0;j<KT;++j){
    cs += __builtin_amdgcn_exp2f((cv[j]-cm)*LOG2E);
    ss += __builtin_amdgcn_exp2f((sw[j]-sm)*LOG2E);
  }
  float lse_c = cm + __logf(cs);
  float lse_s = sm + __logf(ss);
  float kl = 0.f;
  #pragma unroll
  for (int j=0;j<KT;++j){
    float lq = sw[j] - lse_s;
    float lp = cv[j] - lse_c;
    kl += __builtin_amdgcn_exp2f(lq*LOG2E)*(lq - lp);
  }
  kl *= (1.0f/KT);
  if (lane == 0) outarr[b] = BETA*kl + ALPHA*inf;
}

// ---------------- Kernel 4: final mean ---------------------------------------
__global__ __launch_bounds__(256) void final_kernel(
    const float* __restrict__ outarr, float* __restrict__ out){
  __shared__ float sh[4];
  int tid = threadIdx.x, lane = tid & 63, wv = tid >> 6;
  float v = 0.f;
  for (int i = tid; i < BATCH; i += 256) v += outarr[i];
  #pragma unroll
  for (int off=1; off<64; off<<=1) v += __shfl_xor(v, off);
  if (lane == 0) sh[wv] = v;
  __syncthreads();
  if (tid == 0) out[0] = (sh[0]+sh[1]+sh[2]+sh[3])*(1.0f/BATCH);
}

extern "C" void kernel_launch(void* const* d_in, const int* in_sizes, int n_in,
                              void* d_out, int out_size, void* d_ws, size_t ws_size,
                              hipStream_t stream){
  const float* feat   = (const float*)d_in[0];
  const float* scores = (const float*)d_in[1];
  // d_in[2] row_sizes: shape-only, unused
  const float* lscale = (const float*)d_in[3];

  float* ws     = (float*)d_ws;
  float* diag   = ws;                                   // 4096
  float* outarr = diag + BATCH;                         // 4096
  float* carr   = outarr + BATCH;                       // 69632
  float* part_m = carr + NTGT;                          // 4096*128
  float* part_s = part_m + (size_t)BATCH*NSLOT;         // 4096*128
  unsigned char* abf8 = (unsigned char*)(part_s + (size_t)BATCH*NSLOT); // 1 MB
  unsigned char* tbf8 = abf8 + (size_t)BATCH*DD;        // 69632*256 fp8

  tconv_kernel<<<NCHUNKT, 256, 0, stream>>>(feat, lscale, abf8, tbf8, carr, diag);
  gemm_lse_kernel<<<dim3(NSPLIT, MBLK), 256, 0, stream>>>(abf8, tbf8, part_m, part_s);
  combine_kernel<<<BATCH/4, 256, 0, stream>>>(part_m, part_s, diag, carr, scores,
                                              lscale, outarr);
  final_kernel<<<1, 256, 0, stream>>>(outarr, (float*)d_out);
}